// Round 8
// baseline (567.529 us; speedup 1.0000x reference)
//
#include <hip/hip_runtime.h>
#include <cstddef>
#include <cstdint>

#define E_TOTAL 3200000
#define N_NODES 100000
#define N_RELS 50
#define N_BASES 16
#define HD 16
#define OD 8
#define NTHR 256

#define NBKT 196       // coarse buckets: dst >> 9 (512 dsts each)
#define BKT_CAP 18000
#define P1_BLOCKS 1024
#define P1_CHUNK 3125  // 1024*3125 = 3.2M

typedef unsigned int u32;
typedef __attribute__((ext_vector_type(8))) short s16x8;
typedef __attribute__((ext_vector_type(4))) float f32x4;

__device__ __forceinline__ float bl16(u32 u) { return __uint_as_float(u << 16); }
__device__ __forceinline__ float bh16(u32 u) { return __uint_as_float(u & 0xffff0000u); }
__device__ __forceinline__ u32 cvtpk(float x0, float x1) {  // v_cvt_pk_bf16_f32 (RNE)
    u32 r;
    asm("v_cvt_pk_bf16_f32 %0, %1, %2" : "=v"(r) : "v"(x0), "v"(x1));
    return r;
}
__device__ __forceinline__ ushort bf16r(float x) {
    u32 a = __float_as_uint(x);
    return (ushort)((a + 0x7fffu + ((a >> 16) & 1u)) >> 16);
}
__device__ __forceinline__ s16x8 as_s16x8(uint4 u) {
    union { uint4 u; s16x8 s; } x; x.u = u; return x.s;
}

// ---------------- MFMA A-operand weight fragments ----------------
// frag[r][lane][e] (ushort, 512/rel): A[o=lane&15][k=(lane>>4)*8+e] = Wr[r][i=k][o], zero for k>=16 (and o>=8 for L2).
__global__ __launch_bounds__(NTHR) void k_wrf(const float* __restrict__ W1, const float* __restrict__ C1,
                                              const float* __restrict__ W2, const float* __restrict__ C2,
                                              ushort* __restrict__ f1, ushort* __restrict__ f2) {
    int idx = blockIdx.x * NTHR + threadIdx.x;
    if (idx >= 2 * N_RELS * 512) return;
    int half = idx / (N_RELS * 512);
    int j = idx % (N_RELS * 512);
    int r = j >> 9, rem = j & 511, lane = rem >> 3, e = rem & 7;
    int o = lane & 15, k = (lane >> 4) * 8 + e;
    float acc = 0.f;
    if (half == 0) {
        if (k < 16) {
            #pragma unroll
            for (int b = 0; b < N_BASES; ++b)
                acc = fmaf(C1[r * N_BASES + b], W1[b * 256 + k * 16 + o], acc);
        }
        f1[j] = bf16r(acc);
    } else {
        if (k < 16 && o < 8) {
            #pragma unroll
            for (int b = 0; b < N_BASES; ++b)
                acc = fmaf(C2[r * N_BASES + b], W2[b * 128 + k * 8 + o], acc);
        }
        f2[j] = bf16r(acc);
    }
}

// fp32 Wr for tier-B fallback
__global__ __launch_bounds__(NTHR) void k_wr(const float* __restrict__ W1, const float* __restrict__ C1,
                                             const float* __restrict__ W2, const float* __restrict__ C2,
                                             float* __restrict__ Wr1, float* __restrict__ Wr2) {
    int idx = blockIdx.x * NTHR + threadIdx.x;
    const int n1 = N_RELS * 256;
    if (idx < n1) {
        int r = idx >> 8, io = idx & 255;
        float acc = 0.f;
        #pragma unroll
        for (int b = 0; b < N_BASES; ++b)
            acc = fmaf(C1[r * N_BASES + b], W1[b * 256 + io], acc);
        Wr1[idx] = acc;
    } else if (idx < n1 + N_RELS * 128) {
        int j = idx - n1;
        int r = j >> 7, io = j & 127;
        float acc = 0.f;
        #pragma unroll
        for (int b = 0; b < N_BASES; ++b)
            acc = fmaf(C2[r * N_BASES + b], W2[b * 128 + io], acc);
        Wr2[j] = acc;
    }
}

// ================= two-level dst-sort =================

__global__ __launch_bounds__(NTHR) void k_p1(const int* __restrict__ esrc, const int* __restrict__ edst,
                                             const int* __restrict__ erel, const float* __restrict__ enorm,
                                             int* __restrict__ bhead, uint2* __restrict__ tmp) {
    __shared__ int lcnt[NBKT], lbase[NBKT], lcur[NBKT];
    int tid = threadIdx.x;
    for (int i = tid; i < NBKT; i += NTHR) { lcnt[i] = 0; lcur[i] = 0; }
    __syncthreads();
    int e0 = blockIdx.x * P1_CHUNK;
    for (int i = tid; i < P1_CHUNK; i += NTHR)
        atomicAdd(&lcnt[edst[e0 + i] >> 9], 1);
    __syncthreads();
    for (int i = tid; i < NBKT; i += NTHR)
        lbase[i] = atomicAdd(&bhead[i * 16], lcnt[i]);
    __syncthreads();
    for (int i = tid; i < P1_CHUNK; i += NTHR) {
        int e = e0 + i;
        int d = edst[e];
        int b = d >> 9;
        int pos = b * BKT_CAP + lbase[b] + atomicAdd(&lcur[b], 1);
        tmp[pos] = make_uint2((u32)esrc[e] | ((u32)erel[e] << 17) | ((u32)(d & 511) << 23),
                              __float_as_uint(enorm[e]));
    }
}

__global__ void k_bscan(const int* __restrict__ bhead, int* __restrict__ bfinal) {
    __shared__ int s[256];
    int tid = threadIdx.x;
    int v = (tid < NBKT) ? bhead[tid * 16] : 0;
    s[tid] = v;
    __syncthreads();
    for (int off = 1; off < 256; off <<= 1) {
        int t = (tid >= off) ? s[tid - off] : 0;
        __syncthreads();
        s[tid] += t;
        __syncthreads();
    }
    if (tid < NBKT) bfinal[tid] = s[tid] - v;  // exclusive
}

__global__ __launch_bounds__(1024) void k_p2(const uint2* __restrict__ tmp, const int* __restrict__ bhead,
                                             const int* __restrict__ bfinal, uint2* __restrict__ rec,
                                             int* __restrict__ row_ptr) {
    int b = blockIdx.x;
    int cnt = bhead[b * 16];
    int gbase = bfinal[b];
    __shared__ int dcnt[512], dscan[512];
    int tid = threadIdx.x;
    if (tid < 512) dcnt[tid] = 0;
    __syncthreads();
    const uint2* tb = tmp + (size_t)b * BKT_CAP;
    for (int i = tid; i < cnt; i += 1024)
        atomicAdd(&dcnt[tb[i].x >> 23], 1);
    __syncthreads();
    if (tid < 512) dscan[tid] = dcnt[tid];
    __syncthreads();
    for (int off = 1; off < 512; off <<= 1) {
        int v = (tid >= off && tid < 512) ? dscan[tid - off] : 0;
        __syncthreads();
        if (tid < 512) dscan[tid] += v;
        __syncthreads();
    }
    if (tid < 512) {
        int excl = gbase + dscan[tid] - dcnt[tid];
        int d = (b << 9) + tid;
        if (d < N_NODES) row_ptr[d] = excl;
        dscan[tid] = excl;  // becomes scatter cursor
    }
    if (b == NBKT - 1 && tid == 0) row_ptr[N_NODES] = E_TOTAL;
    __syncthreads();
    for (int i = tid; i < cnt; i += 1024) {
        uint2 t = tb[i];
        int pos = atomicAdd(&dscan[t.x >> 23], 1);
        rec[pos] = make_uint2(t.x & 0x7FFFFFu, t.y);
    }
}

// ================= dense embedding tables =================

// emb0[r][n][h] = sum_b C0[r,b]*W0[b,n,h], bf16.
__global__ __launch_bounds__(NTHR) void k_emb0(const float* __restrict__ W0, const float* __restrict__ C0,
                                               ushort* __restrict__ emb) {
    int t = threadIdx.x;
    size_t base = (size_t)blockIdx.x * 256 + t;  // n*16+h
    float w[16];
    #pragma unroll
    for (int b = 0; b < 16; ++b) w[b] = W0[(size_t)b * (N_NODES * HD) + base];
    __shared__ float c[N_RELS * 16];
    for (int i = t; i < N_RELS * 16; i += NTHR) c[i] = C0[i];
    __syncthreads();
    for (int r = 0; r < N_RELS; ++r) {
        const float* cr = c + r * 16;
        float v = 0.f;
        #pragma unroll
        for (int b = 0; b < 16; ++b) v = fmaf(cr[b], w[b], v);
        emb[(size_t)r * (N_NODES * HD) + base] = bf16r(v);
    }
}

// gather-accumulate 16-dim bf16 rows by (rel,src), relu-fused, bf16x16 row out (32B).
__global__ __launch_bounds__(NTHR) void k_g16b(const uint2* __restrict__ rec, const int* __restrict__ row_ptr,
                                               const ushort* __restrict__ tbl, u32* __restrict__ hb) {
    int lane = threadIdx.x & 63;
    int g = lane >> 3, l = lane & 7;
    int wave = (blockIdx.x * NTHR + threadIdx.x) >> 6;
    int nw = (gridDim.x * NTHR) >> 6;
    for (int d = wave; d < N_NODES; d += nw) {
        int s0 = row_ptr[d], s1 = row_ptr[d + 1];
        float a0 = 0.f, a1 = 0.f;
        for (int j = s0 + g; j < s1; j += 8) {
            uint2 rc = rec[j];
            int src = rc.x & 0x1FFFF;
            int rel = rc.x >> 17;
            float nm = __uint_as_float(rc.y);
            u32 q = *(const u32*)(tbl + ((size_t)rel * N_NODES + src) * HD + l * 2);
            a0 = fmaf(nm, bl16(q), a0);
            a1 = fmaf(nm, bh16(q), a1);
        }
        a0 += __shfl_xor(a0, 8);  a1 += __shfl_xor(a1, 8);
        a0 += __shfl_xor(a0, 16); a1 += __shfl_xor(a1, 16);
        a0 += __shfl_xor(a0, 32); a1 += __shfl_xor(a1, 32);
        if (lane < 8)
            hb[(size_t)d * 8 + l] = cvtpk(fmaxf(a0, 0.f), fmaxf(a1, 0.f));  // fused relu, bf16 pair
    }
}

// emb1 via MFMA: D[o][node] = Wr1[r] (16xK) x h (Kx16nodes), K=32 (16 real).
// 4000 waves: rel = w/80, tile stride 80 over 6250 16-node tiles.
__global__ __launch_bounds__(NTHR) void k_e1f(const uint4* __restrict__ wfrag, const uint4* __restrict__ hb,
                                              ushort* __restrict__ emb) {
    int lane = threadIdx.x & 63;
    int w = (blockIdx.x * NTHR + threadIdx.x) >> 6;
    int rel = w / 80, c = w % 80;
    s16x8 af = as_s16x8(wfrag[rel * 64 + lane]);  // A fragment (weights)
    int col = lane & 15, ks = lane >> 4;
    bool hval = ks < 2;
    const uint4 zero4 = make_uint4(0, 0, 0, 0);
    for (int t = c; t < 6250; t += 80) {
        int n = t * 16 + col;
        s16x8 bf = as_s16x8(hval ? hb[(size_t)n * 2 + ks] : zero4);  // B fragment (h row k-slice)
        f32x4 d = __builtin_amdgcn_mfma_f32_16x16x32_bf16(af, bf, (f32x4){0.f, 0.f, 0.f, 0.f}, 0, 0, 0);
        // D: col=lane&15 -> node, row=ks*4+j -> o. Pack 4 outputs (consecutive o) into 8B.
        uint2 pk = make_uint2(cvtpk(d[0], d[1]), cvtpk(d[2], d[3]));
        *(uint2*)(emb + ((size_t)rel * N_NODES + n) * 16 + ks * 4) = pk;
    }
}

// emb2 via MFMA: same, o<8 valid (ks<2 lanes write).
__global__ __launch_bounds__(NTHR) void k_e2f(const uint4* __restrict__ wfrag, const uint4* __restrict__ hb,
                                              ushort* __restrict__ emb) {
    int lane = threadIdx.x & 63;
    int w = (blockIdx.x * NTHR + threadIdx.x) >> 6;
    int rel = w / 40, c = w % 40;
    s16x8 af = as_s16x8(wfrag[rel * 64 + lane]);
    int col = lane & 15, ks = lane >> 4;
    bool hval = ks < 2;
    const uint4 zero4 = make_uint4(0, 0, 0, 0);
    for (int t = c; t < 6250; t += 40) {
        int n = t * 16 + col;
        s16x8 bf = as_s16x8(hval ? hb[(size_t)n * 2 + ks] : zero4);
        f32x4 d = __builtin_amdgcn_mfma_f32_16x16x32_bf16(af, bf, (f32x4){0.f, 0.f, 0.f, 0.f}, 0, 0, 0);
        if (ks < 2) {  // o = ks*4+j in [0,8)
            uint2 pk = make_uint2(cvtpk(d[0], d[1]), cvtpk(d[2], d[3]));
            *(uint2*)(emb + ((size_t)rel * N_NODES + n) * OD + ks * 4) = pk;
        }
    }
}

// gather 8-dim bf16 rows + fused softmax. 16 edge-groups x 4 lanes.
__global__ __launch_bounds__(NTHR) void k_g8sm(const uint2* __restrict__ rec, const int* __restrict__ row_ptr,
                                               const ushort* __restrict__ tbl, float* __restrict__ out) {
    int lane = threadIdx.x & 63;
    int g = lane >> 2, l = lane & 3;
    int wave = (blockIdx.x * NTHR + threadIdx.x) >> 6;
    int nw = (gridDim.x * NTHR) >> 6;
    for (int d = wave; d < N_NODES; d += nw) {
        int s0 = row_ptr[d], s1 = row_ptr[d + 1];
        float a0 = 0.f, a1 = 0.f;
        for (int j = s0 + g; j < s1; j += 16) {
            uint2 rc = rec[j];
            int src = rc.x & 0x1FFFF;
            int rel = rc.x >> 17;
            float nm = __uint_as_float(rc.y);
            u32 q = *(const u32*)(tbl + ((size_t)rel * N_NODES + src) * OD + l * 2);
            a0 = fmaf(nm, bl16(q), a0);
            a1 = fmaf(nm, bh16(q), a1);
        }
        a0 += __shfl_xor(a0, 4);  a1 += __shfl_xor(a1, 4);
        a0 += __shfl_xor(a0, 8);  a1 += __shfl_xor(a1, 8);
        a0 += __shfl_xor(a0, 16); a1 += __shfl_xor(a1, 16);
        a0 += __shfl_xor(a0, 32); a1 += __shfl_xor(a1, 32);
        float mm = fmaxf(a0, a1);
        mm = fmaxf(mm, __shfl_xor(mm, 1));
        mm = fmaxf(mm, __shfl_xor(mm, 2));
        float e0 = __expf(a0 - mm), e1 = __expf(a1 - mm);
        float s = e0 + e1;
        s += __shfl_xor(s, 1);
        s += __shfl_xor(s, 2);
        float inv = 1.0f / s;
        if (lane < 4)
            *(float2*)(out + (size_t)d * OD + l * 2) = make_float2(e0 * inv, e1 * inv);
    }
}

// ======= TIER B fallback (atomics, 16.1 MB) =======
#define NBLK 2560

__device__ __forceinline__ void fma4(float* acc, float c, float4 w) {
    acc[0] = fmaf(c, w.x, acc[0]);
    acc[1] = fmaf(c, w.y, acc[1]);
    acc[2] = fmaf(c, w.z, acc[2]);
    acc[3] = fmaf(c, w.w, acc[3]);
}

__global__ __launch_bounds__(NTHR) void k_l0_old(const int* __restrict__ esrc, const int* __restrict__ edst,
                                                 const int* __restrict__ erel, const float* __restrict__ enorm,
                                                 const float* __restrict__ W0, const float* __restrict__ C0,
                                                 float* __restrict__ h0) {
    for (int e = blockIdx.x * NTHR + threadIdx.x; e < E_TOTAL; e += NBLK * NTHR) {
        int s = esrc[e], d = edst[e], r = erel[e];
        float nm = enorm[e];
        const float4* cp = reinterpret_cast<const float4*>(C0 + r * N_BASES);
        float4 c0 = cp[0], c1 = cp[1], c2 = cp[2], c3 = cp[3];
        float coef[16] = {c0.x, c0.y, c0.z, c0.w, c1.x, c1.y, c1.z, c1.w,
                          c2.x, c2.y, c2.z, c2.w, c3.x, c3.y, c3.z, c3.w};
        float acc[16];
        #pragma unroll
        for (int h = 0; h < 16; ++h) acc[h] = 0.f;
        const float* wbase = W0 + (size_t)s * HD;
        #pragma unroll
        for (int b = 0; b < N_BASES; ++b) {
            const float4* wp = reinterpret_cast<const float4*>(wbase + (size_t)b * (N_NODES * HD));
            float cb = coef[b];
            fma4(acc + 0, cb, wp[0]);
            fma4(acc + 4, cb, wp[1]);
            fma4(acc + 8, cb, wp[2]);
            fma4(acc + 12, cb, wp[3]);
        }
        float* outp = h0 + (size_t)d * HD;
        #pragma unroll
        for (int h = 0; h < 16; ++h) atomicAdd(outp + h, nm * acc[h]);
    }
}

__global__ __launch_bounds__(NTHR) void k_l1_old(const int* __restrict__ esrc, const int* __restrict__ edst,
                                                 const int* __restrict__ erel, const float* __restrict__ enorm,
                                                 const float* __restrict__ h0, const float* __restrict__ Wr1,
                                                 float* __restrict__ h1) {
    __shared__ float w[N_RELS * 260];
    for (int i = threadIdx.x; i < N_RELS * 256; i += NTHR) {
        int r = i >> 8, rest = i & 255;
        w[r * 260 + rest] = Wr1[i];
    }
    __syncthreads();
    for (int e = blockIdx.x * NTHR + threadIdx.x; e < E_TOTAL; e += NBLK * NTHR) {
        int s = esrc[e], d = edst[e], r = erel[e];
        float nm = enorm[e];
        const float4* hp = reinterpret_cast<const float4*>(h0 + (size_t)s * HD);
        float4 hv0 = hp[0], hv1 = hp[1], hv2 = hp[2], hv3 = hp[3];
        float hs[16] = {fmaxf(hv0.x, 0.f), fmaxf(hv0.y, 0.f), fmaxf(hv0.z, 0.f), fmaxf(hv0.w, 0.f),
                        fmaxf(hv1.x, 0.f), fmaxf(hv1.y, 0.f), fmaxf(hv1.z, 0.f), fmaxf(hv1.w, 0.f),
                        fmaxf(hv2.x, 0.f), fmaxf(hv2.y, 0.f), fmaxf(hv2.z, 0.f), fmaxf(hv2.w, 0.f),
                        fmaxf(hv3.x, 0.f), fmaxf(hv3.y, 0.f), fmaxf(hv3.z, 0.f), fmaxf(hv3.w, 0.f)};
        float acc[16];
        #pragma unroll
        for (int h = 0; h < 16; ++h) acc[h] = 0.f;
        const float* wr = w + r * 260;
        #pragma unroll
        for (int i = 0; i < 16; ++i) {
            float hi = hs[i];
            const float4* wp = reinterpret_cast<const float4*>(wr + i * 16);
            fma4(acc + 0, hi, wp[0]);
            fma4(acc + 4, hi, wp[1]);
            fma4(acc + 8, hi, wp[2]);
            fma4(acc + 12, hi, wp[3]);
        }
        float* outp = h1 + (size_t)d * HD;
        #pragma unroll
        for (int h = 0; h < 16; ++h) atomicAdd(outp + h, nm * acc[h]);
    }
}

__global__ __launch_bounds__(NTHR) void k_l2_old(const int* __restrict__ esrc, const int* __restrict__ edst,
                                                 const int* __restrict__ erel, const float* __restrict__ enorm,
                                                 const float* __restrict__ h1, const float* __restrict__ Wr2,
                                                 float* __restrict__ h2) {
    __shared__ float w[N_RELS * 132];
    for (int i = threadIdx.x; i < N_RELS * 128; i += NTHR) {
        int r = i >> 7, rest = i & 127;
        w[r * 132 + rest] = Wr2[i];
    }
    __syncthreads();
    for (int e = blockIdx.x * NTHR + threadIdx.x; e < E_TOTAL; e += NBLK * NTHR) {
        int s = esrc[e], d = edst[e], r = erel[e];
        float nm = enorm[e];
        const float4* hp = reinterpret_cast<const float4*>(h1 + (size_t)s * HD);
        float4 hv0 = hp[0], hv1 = hp[1], hv2 = hp[2], hv3 = hp[3];
        float hs[16] = {fmaxf(hv0.x, 0.f), fmaxf(hv0.y, 0.f), fmaxf(hv0.z, 0.f), fmaxf(hv0.w, 0.f),
                        fmaxf(hv1.x, 0.f), fmaxf(hv1.y, 0.f), fmaxf(hv1.z, 0.f), fmaxf(hv1.w, 0.f),
                        fmaxf(hv2.x, 0.f), fmaxf(hv2.y, 0.f), fmaxf(hv2.z, 0.f), fmaxf(hv2.w, 0.f),
                        fmaxf(hv3.x, 0.f), fmaxf(hv3.y, 0.f), fmaxf(hv3.z, 0.f), fmaxf(hv3.w, 0.f)};
        float acc[8];
        #pragma unroll
        for (int h = 0; h < 8; ++h) acc[h] = 0.f;
        const float* wr = w + r * 132;
        #pragma unroll
        for (int i = 0; i < 16; ++i) {
            float hi = hs[i];
            const float4* wp = reinterpret_cast<const float4*>(wr + i * 8);
            fma4(acc + 0, hi, wp[0]);
            fma4(acc + 4, hi, wp[1]);
        }
        float* outp = h2 + (size_t)d * OD;
        #pragma unroll
        for (int h = 0; h < 8; ++h) atomicAdd(outp + h, nm * acc[h]);
    }
}

__global__ __launch_bounds__(NTHR) void k_softmax(const float* __restrict__ h2, float* __restrict__ out) {
    int n = blockIdx.x * NTHR + threadIdx.x;
    if (n >= N_NODES) return;
    const float4* p = reinterpret_cast<const float4*>(h2 + (size_t)n * OD);
    float4 a = p[0], b = p[1];
    float v[8] = {a.x, a.y, a.z, a.w, b.x, b.y, b.z, b.w};
    float m = v[0];
    #pragma unroll
    for (int i = 1; i < 8; ++i) m = fmaxf(m, v[i]);
    float ssum = 0.f;
    #pragma unroll
    for (int i = 0; i < 8; ++i) {
        v[i] = __expf(v[i] - m);
        ssum += v[i];
    }
    float inv = 1.0f / ssum;
    float4* q = reinterpret_cast<float4*>(out + (size_t)n * OD);
    q[0] = make_float4(v[0] * inv, v[1] * inv, v[2] * inv, v[3] * inv);
    q[1] = make_float4(v[4] * inv, v[5] * inv, v[6] * inv, v[7] * inv);
}

// =========================================================================

extern "C" void kernel_launch(void* const* d_in, const int* in_sizes, int n_in,
                              void* d_out, int out_size, void* d_ws, size_t ws_size,
                              hipStream_t stream) {
    const int* esrc = (const int*)d_in[0];
    const int* edst = (const int*)d_in[1];
    const int* erel = (const int*)d_in[2];
    const float* enorm = (const float*)d_in[3];
    const float* W0 = (const float*)d_in[4];
    const float* C0 = (const float*)d_in[5];
    const float* W1 = (const float*)d_in[6];
    const float* C1 = (const float*)d_in[7];
    const float* W2 = (const float*)d_in[8];
    const float* C2 = (const float*)d_in[9];
    const int nsb = (N_NODES + NTHR - 1) / NTHR;  // 391

    if (ws_size >= (size_t)201000000) {
        char* wsb = (char*)d_ws;
        ushort* emb = (ushort*)wsb;                       // 160,000,000 B (emb0/emb1 160MB; emb2 reuses 80MB)
        uint2* tmp = (uint2*)wsb;                         //  28,224,000 B (aliases emb; used before emb0)
        uint2* rec = (uint2*)(wsb + 160000000);           //  25,600,000
        u32* h0b = (u32*)(wsb + 185600000);               //   3,200,000 (bf16x16 rows)
        u32* h1b = (u32*)(wsb + 188800000);               //   3,200,000
        ushort* wf1 = (ushort*)(wsb + 192000000);         //      51,200 (MFMA A-frag, L1)
        ushort* wf2 = (ushort*)(wsb + 192051200);         //      51,200 (MFMA A-frag, L2)
        int* row_ptr = (int*)(wsb + 192102400);           //     400,004
        int* bhead = (int*)(wsb + 192502404);             //      12,544 (196 x 16-int padded)
        int* bfinal = (int*)(wsb + 192514948);            //         784

        hipMemsetAsync(bhead, 0, NBKT * 16 * sizeof(int), stream);
        k_p1<<<P1_BLOCKS, NTHR, 0, stream>>>(esrc, edst, erel, enorm, bhead, tmp);
        k_bscan<<<1, 256, 0, stream>>>(bhead, bfinal);
        k_p2<<<NBKT, 1024, 0, stream>>>(tmp, bhead, bfinal, rec, row_ptr);
        k_wrf<<<200, NTHR, 0, stream>>>(W1, C1, W2, C2, wf1, wf2);

        k_emb0<<<N_NODES * HD / NTHR, NTHR, 0, stream>>>(W0, C0, emb);
        k_g16b<<<6250, NTHR, 0, stream>>>(rec, row_ptr, emb, h0b);
        k_e1f<<<1000, NTHR, 0, stream>>>((const uint4*)wf1, (const uint4*)h0b, emb);
        k_g16b<<<6250, NTHR, 0, stream>>>(rec, row_ptr, emb, h1b);
        k_e2f<<<500, NTHR, 0, stream>>>((const uint4*)wf2, (const uint4*)h1b, emb);
        k_g8sm<<<6250, NTHR, 0, stream>>>(rec, row_ptr, emb, (float*)d_out);
    } else {
        // ---- Tier B: atomics fallback ----
        float* ws = (float*)d_ws;
        float* h0 = ws;
        float* h1 = ws + 1600000;
        float* h2 = ws + 3200000;
        float* Wr1 = ws + 4000000;
        float* Wr2 = ws + 4012800;

        hipMemsetAsync(h0, 0, (size_t)4000000 * sizeof(float), stream);
        k_wr<<<75, NTHR, 0, stream>>>(W1, C1, W2, C2, Wr1, Wr2);
        k_l0_old<<<NBLK, NTHR, 0, stream>>>(esrc, edst, erel, enorm, W0, C0, h0);
        k_l1_old<<<NBLK, NTHR, 0, stream>>>(esrc, edst, erel, enorm, h0, Wr1, h1);
        k_l2_old<<<NBLK, NTHR, 0, stream>>>(esrc, edst, erel, enorm, h1, Wr2, h2);
        k_softmax<<<nsb, NTHR, 0, stream>>>(h2, (float*)d_out);
    }
}

// Round 9
// 519.077 us; speedup vs baseline: 1.0933x; 1.0933x over previous
//
#include <hip/hip_runtime.h>
#include <cstddef>
#include <cstdint>

#define E_TOTAL 3200000
#define N_NODES 100000
#define N_RELS 50
#define N_BASES 16
#define HD 16
#define OD 8
#define NTHR 256

#define NBKT 196       // coarse buckets: dst >> 9 (512 dsts each)
#define P1B 1024       // p1 blocks
#define P1C 3125       // edges per p1 block (1024*3125 = 3.2M)

typedef unsigned int u32;
typedef __attribute__((ext_vector_type(8))) short s16x8;
typedef __attribute__((ext_vector_type(4))) float f32x4;

__device__ __forceinline__ float bl16(u32 u) { return __uint_as_float(u << 16); }
__device__ __forceinline__ float bh16(u32 u) { return __uint_as_float(u & 0xffff0000u); }
__device__ __forceinline__ u32 cvtpk(float x0, float x1) {  // v_cvt_pk_bf16_f32 (RNE)
    u32 r;
    asm("v_cvt_pk_bf16_f32 %0, %1, %2" : "=v"(r) : "v"(x0), "v"(x1));
    return r;
}
__device__ __forceinline__ ushort bf16r(float x) {
    u32 a = __float_as_uint(x);
    return (ushort)((a + 0x7fffu + ((a >> 16) & 1u)) >> 16);
}
__device__ __forceinline__ s16x8 as_s16x8(uint4 u) {
    union { uint4 u; s16x8 s; } x; x.u = u; return x.s;
}

// ---------------- MFMA A-operand weight fragments ----------------
__global__ __launch_bounds__(NTHR) void k_wrf(const float* __restrict__ W1, const float* __restrict__ C1,
                                              const float* __restrict__ W2, const float* __restrict__ C2,
                                              ushort* __restrict__ f1, ushort* __restrict__ f2) {
    int idx = blockIdx.x * NTHR + threadIdx.x;
    if (idx >= 2 * N_RELS * 512) return;
    int half = idx / (N_RELS * 512);
    int j = idx % (N_RELS * 512);
    int r = j >> 9, rem = j & 511, lane = rem >> 3, e = rem & 7;
    int o = lane & 15, k = (lane >> 4) * 8 + e;
    float acc = 0.f;
    if (half == 0) {
        if (k < 16) {
            #pragma unroll
            for (int b = 0; b < N_BASES; ++b)
                acc = fmaf(C1[r * N_BASES + b], W1[b * 256 + k * 16 + o], acc);
        }
        f1[j] = bf16r(acc);
    } else {
        if (k < 16 && o < 8) {
            #pragma unroll
            for (int b = 0; b < N_BASES; ++b)
                acc = fmaf(C2[r * N_BASES + b], W2[b * 128 + k * 8 + o], acc);
        }
        f2[j] = bf16r(acc);
    }
}

// fp32 Wr for tier-B fallback
__global__ __launch_bounds__(NTHR) void k_wr(const float* __restrict__ W1, const float* __restrict__ C1,
                                             const float* __restrict__ W2, const float* __restrict__ C2,
                                             float* __restrict__ Wr1, float* __restrict__ Wr2) {
    int idx = blockIdx.x * NTHR + threadIdx.x;
    const int n1 = N_RELS * 256;
    if (idx < n1) {
        int r = idx >> 8, io = idx & 255;
        float acc = 0.f;
        #pragma unroll
        for (int b = 0; b < N_BASES; ++b)
            acc = fmaf(C1[r * N_BASES + b], W1[b * 256 + io], acc);
        Wr1[idx] = acc;
    } else if (idx < n1 + N_RELS * 128) {
        int j = idx - n1;
        int r = j >> 7, io = j & 127;
        float acc = 0.f;
        #pragma unroll
        for (int b = 0; b < N_BASES; ++b)
            acc = fmaf(C2[r * N_BASES + b], W2[b * 128 + io], acc);
        Wr2[j] = acc;
    }
}

// ================= dst-sort v2: dense-write two-level =================

// p1: block-private contiguous output slice; LDS-staged, fully coalesced flush; no global atomics.
__global__ __launch_bounds__(NTHR) void k_p1(const int* __restrict__ esrc, const int* __restrict__ edst,
                                             const int* __restrict__ erel, const float* __restrict__ enorm,
                                             uint2* __restrict__ tmp, int* __restrict__ cntK,
                                             int* __restrict__ runstartK) {
    __shared__ int lcnt[NBKT];
    __shared__ int sc[NTHR];
    __shared__ int lcur[NBKT];
    __shared__ uint2 stage[P1C];  // 25 KB
    int tid = threadIdx.x;
    for (int i = tid; i < NBKT; i += NTHR) lcnt[i] = 0;
    __syncthreads();
    int e0 = blockIdx.x * P1C;
    u32 rx[13], rn[13];
    int rb[13];
    #pragma unroll
    for (int j = 0; j < 13; ++j) {
        int i = tid + j * NTHR;
        rb[j] = -1;
        if (i < P1C) {
            int e = e0 + i;
            int d = edst[e];
            int b = d >> 9;
            rb[j] = b;
            rx[j] = (u32)esrc[e] | ((u32)erel[e] << 17) | ((u32)(d & 511) << 23);
            rn[j] = __float_as_uint(enorm[e]);
            atomicAdd(&lcnt[b], 1);
        }
    }
    __syncthreads();
    // exclusive scan of 196 bucket counts
    int own = (tid < NBKT) ? lcnt[tid] : 0;
    sc[tid] = own;
    __syncthreads();
    #pragma unroll
    for (int off = 1; off < NTHR; off <<= 1) {
        int t = (tid >= off) ? sc[tid - off] : 0;
        __syncthreads();
        sc[tid] += t;
        __syncthreads();
    }
    if (tid < NBKT) lcur[tid] = sc[tid] - own;  // exclusive offset = cursor
    __syncthreads();
    // scatter to LDS staging
    #pragma unroll
    for (int j = 0; j < 13; ++j) {
        if (rb[j] >= 0) {
            int pos = atomicAdd(&lcur[rb[j]], 1);
            stage[pos] = make_uint2(rx[j], rn[j]);
        }
    }
    __syncthreads();
    // linear coalesced flush
    for (int i = tid; i < P1C; i += NTHR)
        tmp[(size_t)blockIdx.x * P1C + i] = stage[i];
    // per-block bucket metadata (k-major: contiguous 784 B per block)
    for (int b = tid; b < NBKT; b += NTHR) {
        int excl = (b < NBKT) ? (lcur[b] - lcnt[b]) : 0;  // lcur advanced by lcnt
        cntK[blockIdx.x * NBKT + b] = lcnt[b];
        runstartK[blockIdx.x * NBKT + b] = blockIdx.x * P1C + excl;
    }
}

// bucket totals: total[b] = sum_k cntK[k][b]
__global__ __launch_bounds__(NTHR) void k_tot(const int* __restrict__ cntK, int* __restrict__ total) {
    int b = blockIdx.x;
    __shared__ int s[NTHR];
    int tid = threadIdx.x;
    int acc = 0;
    for (int k = tid; k < P1B; k += NTHR) acc += cntK[k * NBKT + b];
    s[tid] = acc;
    __syncthreads();
    for (int off = NTHR / 2; off > 0; off >>= 1) {
        if (tid < off) s[tid] += s[tid + off];
        __syncthreads();
    }
    if (tid == 0) total[b] = s[0];
}

__global__ void k_bscan(const int* __restrict__ total, int* __restrict__ base) {
    __shared__ int s[256];
    int tid = threadIdx.x;
    int v = (tid < NBKT) ? total[tid] : 0;
    s[tid] = v;
    __syncthreads();
    for (int off = 1; off < 256; off <<= 1) {
        int t = (tid >= off) ? s[tid - off] : 0;
        __syncthreads();
        s[tid] += t;
        __syncthreads();
    }
    if (tid < NBKT) base[tid] = s[tid] - v;  // exclusive
}

// p2: 1024 threads = 1024 runs; pass A hist, scan, pass B scatter into L2-resident bucket window.
__global__ __launch_bounds__(1024) void k_p2(const uint2* __restrict__ tmp, const int* __restrict__ cntK,
                                             const int* __restrict__ runstartK, const int* __restrict__ base,
                                             uint2* __restrict__ rec, int* __restrict__ row_ptr) {
    int b = blockIdx.x;
    int tid = threadIdx.x;
    int mycnt = cntK[tid * NBKT + b];
    int myrs = runstartK[tid * NBKT + b];
    int gbase = base[b];
    __shared__ int dcnt[512], dscan[512];
    if (tid < 512) dcnt[tid] = 0;
    __syncthreads();
    for (int i = 0; i < mycnt; ++i)
        atomicAdd(&dcnt[tmp[myrs + i].x >> 23], 1);
    __syncthreads();
    if (tid < 512) dscan[tid] = dcnt[tid];
    __syncthreads();
    for (int off = 1; off < 512; off <<= 1) {
        int v = (tid >= off && tid < 512) ? dscan[tid - off] : 0;
        __syncthreads();
        if (tid < 512) dscan[tid] += v;
        __syncthreads();
    }
    if (tid < 512) {
        int excl = gbase + dscan[tid] - dcnt[tid];
        int d = (b << 9) + tid;
        if (d < N_NODES) row_ptr[d] = excl;
        dscan[tid] = excl;  // scatter cursor
    }
    if (b == NBKT - 1 && tid == 0) row_ptr[N_NODES] = E_TOTAL;
    __syncthreads();
    for (int i = 0; i < mycnt; ++i) {
        uint2 t = tmp[myrs + i];
        int pos = atomicAdd(&dscan[t.x >> 23], 1);
        rec[pos] = make_uint2(t.x & 0x7FFFFFu, t.y);
    }
}

// ================= dense embedding tables =================

// emb0[r][n][h] = sum_b C0[r,b]*W0[b,n,h], bf16.
__global__ __launch_bounds__(NTHR) void k_emb0(const float* __restrict__ W0, const float* __restrict__ C0,
                                               ushort* __restrict__ emb) {
    int t = threadIdx.x;
    size_t base = (size_t)blockIdx.x * 256 + t;  // n*16+h
    float w[16];
    #pragma unroll
    for (int b = 0; b < 16; ++b) w[b] = W0[(size_t)b * (N_NODES * HD) + base];
    __shared__ float c[N_RELS * 16];
    for (int i = t; i < N_RELS * 16; i += NTHR) c[i] = C0[i];
    __syncthreads();
    for (int r = 0; r < N_RELS; ++r) {
        const float* cr = c + r * 16;
        float v = 0.f;
        #pragma unroll
        for (int b = 0; b < 16; ++b) v = fmaf(cr[b], w[b], v);
        emb[(size_t)r * (N_NODES * HD) + base] = bf16r(v);
    }
}

// gather-accumulate 16-dim bf16 rows by (rel,src), relu-fused, bf16x16 row out (32B).
__global__ __launch_bounds__(NTHR) void k_g16b(const uint2* __restrict__ rec, const int* __restrict__ row_ptr,
                                               const ushort* __restrict__ tbl, u32* __restrict__ hb) {
    int lane = threadIdx.x & 63;
    int g = lane >> 3, l = lane & 7;
    int wave = (blockIdx.x * NTHR + threadIdx.x) >> 6;
    int nw = (gridDim.x * NTHR) >> 6;
    for (int d = wave; d < N_NODES; d += nw) {
        int s0 = row_ptr[d], s1 = row_ptr[d + 1];
        float a0 = 0.f, a1 = 0.f;
        for (int j = s0 + g; j < s1; j += 8) {
            uint2 rc = rec[j];
            int src = rc.x & 0x1FFFF;
            int rel = rc.x >> 17;
            float nm = __uint_as_float(rc.y);
            u32 q = *(const u32*)(tbl + ((size_t)rel * N_NODES + src) * HD + l * 2);
            a0 = fmaf(nm, bl16(q), a0);
            a1 = fmaf(nm, bh16(q), a1);
        }
        a0 += __shfl_xor(a0, 8);  a1 += __shfl_xor(a1, 8);
        a0 += __shfl_xor(a0, 16); a1 += __shfl_xor(a1, 16);
        a0 += __shfl_xor(a0, 32); a1 += __shfl_xor(a1, 32);
        if (lane < 8)
            hb[(size_t)d * 8 + l] = cvtpk(fmaxf(a0, 0.f), fmaxf(a1, 0.f));  // fused relu
    }
}

// emb1 via MFMA: D[o][node] = Wr1[r] (16xK) x h (Kx16nodes), K=32 (16 real). 8000 waves.
__global__ __launch_bounds__(NTHR) void k_e1f(const uint4* __restrict__ wfrag, const uint4* __restrict__ hb,
                                              ushort* __restrict__ emb) {
    int lane = threadIdx.x & 63;
    int w = (blockIdx.x * NTHR + threadIdx.x) >> 6;
    int rel = w / 160, c = w % 160;
    s16x8 af = as_s16x8(wfrag[rel * 64 + lane]);
    int col = lane & 15, ks = lane >> 4;
    bool hval = ks < 2;
    const uint4 zero4 = make_uint4(0, 0, 0, 0);
    for (int t = c; t < 6250; t += 160) {
        int n = t * 16 + col;
        s16x8 bf = as_s16x8(hval ? hb[(size_t)n * 2 + ks] : zero4);
        f32x4 d = __builtin_amdgcn_mfma_f32_16x16x32_bf16(af, bf, (f32x4){0.f, 0.f, 0.f, 0.f}, 0, 0, 0);
        uint2 pk = make_uint2(cvtpk(d[0], d[1]), cvtpk(d[2], d[3]));
        *(uint2*)(emb + ((size_t)rel * N_NODES + n) * 16 + ks * 4) = pk;
    }
}

// emb2 via MFMA: o<8 valid (ks<2 lanes write). 4000 waves.
__global__ __launch_bounds__(NTHR) void k_e2f(const uint4* __restrict__ wfrag, const uint4* __restrict__ hb,
                                              ushort* __restrict__ emb) {
    int lane = threadIdx.x & 63;
    int w = (blockIdx.x * NTHR + threadIdx.x) >> 6;
    int rel = w / 80, c = w % 80;
    s16x8 af = as_s16x8(wfrag[rel * 64 + lane]);
    int col = lane & 15, ks = lane >> 4;
    bool hval = ks < 2;
    const uint4 zero4 = make_uint4(0, 0, 0, 0);
    for (int t = c; t < 6250; t += 80) {
        int n = t * 16 + col;
        s16x8 bf = as_s16x8(hval ? hb[(size_t)n * 2 + ks] : zero4);
        f32x4 d = __builtin_amdgcn_mfma_f32_16x16x32_bf16(af, bf, (f32x4){0.f, 0.f, 0.f, 0.f}, 0, 0, 0);
        if (ks < 2) {
            uint2 pk = make_uint2(cvtpk(d[0], d[1]), cvtpk(d[2], d[3]));
            *(uint2*)(emb + ((size_t)rel * N_NODES + n) * OD + ks * 4) = pk;
        }
    }
}

// gather 8-dim bf16 rows + fused softmax. 16 edge-groups x 4 lanes.
__global__ __launch_bounds__(NTHR) void k_g8sm(const uint2* __restrict__ rec, const int* __restrict__ row_ptr,
                                               const ushort* __restrict__ tbl, float* __restrict__ out) {
    int lane = threadIdx.x & 63;
    int g = lane >> 2, l = lane & 3;
    int wave = (blockIdx.x * NTHR + threadIdx.x) >> 6;
    int nw = (gridDim.x * NTHR) >> 6;
    for (int d = wave; d < N_NODES; d += nw) {
        int s0 = row_ptr[d], s1 = row_ptr[d + 1];
        float a0 = 0.f, a1 = 0.f;
        for (int j = s0 + g; j < s1; j += 16) {
            uint2 rc = rec[j];
            int src = rc.x & 0x1FFFF;
            int rel = rc.x >> 17;
            float nm = __uint_as_float(rc.y);
            u32 q = *(const u32*)(tbl + ((size_t)rel * N_NODES + src) * OD + l * 2);
            a0 = fmaf(nm, bl16(q), a0);
            a1 = fmaf(nm, bh16(q), a1);
        }
        a0 += __shfl_xor(a0, 4);  a1 += __shfl_xor(a1, 4);
        a0 += __shfl_xor(a0, 8);  a1 += __shfl_xor(a1, 8);
        a0 += __shfl_xor(a0, 16); a1 += __shfl_xor(a1, 16);
        a0 += __shfl_xor(a0, 32); a1 += __shfl_xor(a1, 32);
        float mm = fmaxf(a0, a1);
        mm = fmaxf(mm, __shfl_xor(mm, 1));
        mm = fmaxf(mm, __shfl_xor(mm, 2));
        float e0 = __expf(a0 - mm), e1 = __expf(a1 - mm);
        float s = e0 + e1;
        s += __shfl_xor(s, 1);
        s += __shfl_xor(s, 2);
        float inv = 1.0f / s;
        if (lane < 4)
            *(float2*)(out + (size_t)d * OD + l * 2) = make_float2(e0 * inv, e1 * inv);
    }
}

// ======= TIER B fallback (atomics, 16.1 MB) =======
#define NBLK 2560

__device__ __forceinline__ void fma4(float* acc, float c, float4 w) {
    acc[0] = fmaf(c, w.x, acc[0]);
    acc[1] = fmaf(c, w.y, acc[1]);
    acc[2] = fmaf(c, w.z, acc[2]);
    acc[3] = fmaf(c, w.w, acc[3]);
}

__global__ __launch_bounds__(NTHR) void k_l0_old(const int* __restrict__ esrc, const int* __restrict__ edst,
                                                 const int* __restrict__ erel, const float* __restrict__ enorm,
                                                 const float* __restrict__ W0, const float* __restrict__ C0,
                                                 float* __restrict__ h0) {
    for (int e = blockIdx.x * NTHR + threadIdx.x; e < E_TOTAL; e += NBLK * NTHR) {
        int s = esrc[e], d = edst[e], r = erel[e];
        float nm = enorm[e];
        const float4* cp = reinterpret_cast<const float4*>(C0 + r * N_BASES);
        float4 c0 = cp[0], c1 = cp[1], c2 = cp[2], c3 = cp[3];
        float coef[16] = {c0.x, c0.y, c0.z, c0.w, c1.x, c1.y, c1.z, c1.w,
                          c2.x, c2.y, c2.z, c2.w, c3.x, c3.y, c3.z, c3.w};
        float acc[16];
        #pragma unroll
        for (int h = 0; h < 16; ++h) acc[h] = 0.f;
        const float* wbase = W0 + (size_t)s * HD;
        #pragma unroll
        for (int b = 0; b < N_BASES; ++b) {
            const float4* wp = reinterpret_cast<const float4*>(wbase + (size_t)b * (N_NODES * HD));
            float cb = coef[b];
            fma4(acc + 0, cb, wp[0]);
            fma4(acc + 4, cb, wp[1]);
            fma4(acc + 8, cb, wp[2]);
            fma4(acc + 12, cb, wp[3]);
        }
        float* outp = h0 + (size_t)d * HD;
        #pragma unroll
        for (int h = 0; h < 16; ++h) atomicAdd(outp + h, nm * acc[h]);
    }
}

__global__ __launch_bounds__(NTHR) void k_l1_old(const int* __restrict__ esrc, const int* __restrict__ edst,
                                                 const int* __restrict__ erel, const float* __restrict__ enorm,
                                                 const float* __restrict__ h0, const float* __restrict__ Wr1,
                                                 float* __restrict__ h1) {
    __shared__ float w[N_RELS * 260];
    for (int i = threadIdx.x; i < N_RELS * 256; i += NTHR) {
        int r = i >> 8, rest = i & 255;
        w[r * 260 + rest] = Wr1[i];
    }
    __syncthreads();
    for (int e = blockIdx.x * NTHR + threadIdx.x; e < E_TOTAL; e += NBLK * NTHR) {
        int s = esrc[e], d = edst[e], r = erel[e];
        float nm = enorm[e];
        const float4* hp = reinterpret_cast<const float4*>(h0 + (size_t)s * HD);
        float4 hv0 = hp[0], hv1 = hp[1], hv2 = hp[2], hv3 = hp[3];
        float hs[16] = {fmaxf(hv0.x, 0.f), fmaxf(hv0.y, 0.f), fmaxf(hv0.z, 0.f), fmaxf(hv0.w, 0.f),
                        fmaxf(hv1.x, 0.f), fmaxf(hv1.y, 0.f), fmaxf(hv1.z, 0.f), fmaxf(hv1.w, 0.f),
                        fmaxf(hv2.x, 0.f), fmaxf(hv2.y, 0.f), fmaxf(hv2.z, 0.f), fmaxf(hv2.w, 0.f),
                        fmaxf(hv3.x, 0.f), fmaxf(hv3.y, 0.f), fmaxf(hv3.z, 0.f), fmaxf(hv3.w, 0.f)};
        float acc[16];
        #pragma unroll
        for (int h = 0; h < 16; ++h) acc[h] = 0.f;
        const float* wr = w + r * 260;
        #pragma unroll
        for (int i = 0; i < 16; ++i) {
            float hi = hs[i];
            const float4* wp = reinterpret_cast<const float4*>(wr + i * 16);
            fma4(acc + 0, hi, wp[0]);
            fma4(acc + 4, hi, wp[1]);
            fma4(acc + 8, hi, wp[2]);
            fma4(acc + 12, hi, wp[3]);
        }
        float* outp = h1 + (size_t)d * HD;
        #pragma unroll
        for (int h = 0; h < 16; ++h) atomicAdd(outp + h, nm * acc[h]);
    }
}

__global__ __launch_bounds__(NTHR) void k_l2_old(const int* __restrict__ esrc, const int* __restrict__ edst,
                                                 const int* __restrict__ erel, const float* __restrict__ enorm,
                                                 const float* __restrict__ h1, const float* __restrict__ Wr2,
                                                 float* __restrict__ h2) {
    __shared__ float w[N_RELS * 132];
    for (int i = threadIdx.x; i < N_RELS * 128; i += NTHR) {
        int r = i >> 7, rest = i & 127;
        w[r * 132 + rest] = Wr2[i];
    }
    __syncthreads();
    for (int e = blockIdx.x * NTHR + threadIdx.x; e < E_TOTAL; e += NBLK * NTHR) {
        int s = esrc[e], d = edst[e], r = erel[e];
        float nm = enorm[e];
        const float4* hp = reinterpret_cast<const float4*>(h1 + (size_t)s * HD);
        float4 hv0 = hp[0], hv1 = hp[1], hv2 = hp[2], hv3 = hp[3];
        float hs[16] = {fmaxf(hv0.x, 0.f), fmaxf(hv0.y, 0.f), fmaxf(hv0.z, 0.f), fmaxf(hv0.w, 0.f),
                        fmaxf(hv1.x, 0.f), fmaxf(hv1.y, 0.f), fmaxf(hv1.z, 0.f), fmaxf(hv1.w, 0.f),
                        fmaxf(hv2.x, 0.f), fmaxf(hv2.y, 0.f), fmaxf(hv2.z, 0.f), fmaxf(hv2.w, 0.f),
                        fmaxf(hv3.x, 0.f), fmaxf(hv3.y, 0.f), fmaxf(hv3.z, 0.f), fmaxf(hv3.w, 0.f)};
        float acc[8];
        #pragma unroll
        for (int h = 0; h < 8; ++h) acc[h] = 0.f;
        const float* wr = w + r * 132;
        #pragma unroll
        for (int i = 0; i < 16; ++i) {
            float hi = hs[i];
            const float4* wp = reinterpret_cast<const float4*>(wr + i * 8);
            fma4(acc + 0, hi, wp[0]);
            fma4(acc + 4, hi, wp[1]);
        }
        float* outp = h2 + (size_t)d * OD;
        #pragma unroll
        for (int h = 0; h < 8; ++h) atomicAdd(outp + h, nm * acc[h]);
    }
}

__global__ __launch_bounds__(NTHR) void k_softmax(const float* __restrict__ h2, float* __restrict__ out) {
    int n = blockIdx.x * NTHR + threadIdx.x;
    if (n >= N_NODES) return;
    const float4* p = reinterpret_cast<const float4*>(h2 + (size_t)n * OD);
    float4 a = p[0], b = p[1];
    float v[8] = {a.x, a.y, a.z, a.w, b.x, b.y, b.z, b.w};
    float m = v[0];
    #pragma unroll
    for (int i = 1; i < 8; ++i) m = fmaxf(m, v[i]);
    float ssum = 0.f;
    #pragma unroll
    for (int i = 0; i < 8; ++i) {
        v[i] = __expf(v[i] - m);
        ssum += v[i];
    }
    float inv = 1.0f / ssum;
    float4* q = reinterpret_cast<float4*>(out + (size_t)n * OD);
    q[0] = make_float4(v[0] * inv, v[1] * inv, v[2] * inv, v[3] * inv);
    q[1] = make_float4(v[4] * inv, v[5] * inv, v[6] * inv, v[7] * inv);
}

// =========================================================================

extern "C" void kernel_launch(void* const* d_in, const int* in_sizes, int n_in,
                              void* d_out, int out_size, void* d_ws, size_t ws_size,
                              hipStream_t stream) {
    const int* esrc = (const int*)d_in[0];
    const int* edst = (const int*)d_in[1];
    const int* erel = (const int*)d_in[2];
    const float* enorm = (const float*)d_in[3];
    const float* W0 = (const float*)d_in[4];
    const float* C0 = (const float*)d_in[5];
    const float* W1 = (const float*)d_in[6];
    const float* C1 = (const float*)d_in[7];
    const float* W2 = (const float*)d_in[8];
    const float* C2 = (const float*)d_in[9];
    const int nsb = (N_NODES + NTHR - 1) / NTHR;  // 391

    if (ws_size >= (size_t)201000000) {
        char* wsb = (char*)d_ws;
        ushort* emb = (ushort*)wsb;                       // 160,000,000 B (emb0/emb1; emb2 reuses 80MB)
        uint2* tmp = (uint2*)wsb;                         //  25,600,000 B (aliases emb; used before emb0)
        uint2* rec = (uint2*)(wsb + 160000000);           //  25,600,000
        u32* h0b = (u32*)(wsb + 185600000);               //   3,200,000 (bf16x16 rows)
        u32* h1b = (u32*)(wsb + 188800000);               //   3,200,000
        ushort* wf1 = (ushort*)(wsb + 192000000);         //      51,200 (MFMA A-frag, L1)
        ushort* wf2 = (ushort*)(wsb + 192051200);         //      51,200 (MFMA A-frag, L2)
        int* row_ptr = (int*)(wsb + 192102400);           //     400,004
        int* cntK = (int*)(wsb + 192502404);              //     802,816 (1024x196, k-major)
        int* runstartK = (int*)(wsb + 193305220);         //     802,816
        int* total = (int*)(wsb + 194108036);             //         784
        int* bbase = (int*)(wsb + 194108820);             //         784

        k_p1<<<P1B, NTHR, 0, stream>>>(esrc, edst, erel, enorm, tmp, cntK, runstartK);
        k_tot<<<NBKT, NTHR, 0, stream>>>(cntK, total);
        k_bscan<<<1, 256, 0, stream>>>(total, bbase);
        k_p2<<<NBKT, 1024, 0, stream>>>(tmp, cntK, runstartK, bbase, rec, row_ptr);
        k_wrf<<<200, NTHR, 0, stream>>>(W1, C1, W2, C2, wf1, wf2);

        k_emb0<<<N_NODES * HD / NTHR, NTHR, 0, stream>>>(W0, C0, emb);
        k_g16b<<<6250, NTHR, 0, stream>>>(rec, row_ptr, emb, h0b);
        k_e1f<<<2000, NTHR, 0, stream>>>((const uint4*)wf1, (const uint4*)h0b, emb);
        k_g16b<<<6250, NTHR, 0, stream>>>(rec, row_ptr, emb, h1b);
        k_e2f<<<1000, NTHR, 0, stream>>>((const uint4*)wf2, (const uint4*)h1b, emb);
        k_g8sm<<<6250, NTHR, 0, stream>>>(rec, row_ptr, emb, (float*)d_out);
    } else {
        // ---- Tier B: atomics fallback ----
        float* ws = (float*)d_ws;
        float* h0 = ws;
        float* h1 = ws + 1600000;
        float* h2 = ws + 3200000;
        float* Wr1 = ws + 4000000;
        float* Wr2 = ws + 4012800;

        hipMemsetAsync(h0, 0, (size_t)4000000 * sizeof(float), stream);
        k_wr<<<75, NTHR, 0, stream>>>(W1, C1, W2, C2, Wr1, Wr2);
        k_l0_old<<<NBLK, NTHR, 0, stream>>>(esrc, edst, erel, enorm, W0, C0, h0);
        k_l1_old<<<NBLK, NTHR, 0, stream>>>(esrc, edst, erel, enorm, h0, Wr1, h1);
        k_l2_old<<<NBLK, NTHR, 0, stream>>>(esrc, edst, erel, enorm, h1, Wr2, h2);
        k_softmax<<<nsb, NTHR, 0, stream>>>(h2, (float*)d_out);
    }
}